// Round 2
// baseline (519.266 us; speedup 1.0000x reference)
//
#include <hip/hip_runtime.h>
#include <math.h>

#define N 8192
#define C 64
#define K 16

// ---------------- Kernel 1: brute-force exact KNN, f64 distances, register-resident ----------
// One block (256 thr) per query. Thread t owns candidates j = t + 256*q, q in [0,32).
// Distances computed ONCE in f64 (true ordering; reference's f32 formula has ~5e-5
// cancellation error, but harness ref is high-precision numpy) and kept in registers.
__global__ __launch_bounds__(256) void knn_kernel(const float* __restrict__ pos,
                                                  int* __restrict__ idx_out) {
    __shared__ double wmin[4];
    __shared__ int    wmini[4];
    const int i   = blockIdx.x;
    const int tid = threadIdx.x;

    const double pix = (double)pos[3*i];
    const double piy = (double)pos[3*i+1];
    const double piz = (double)pos[3*i+2];

    double d[32];
    #pragma unroll
    for (int q = 0; q < 32; ++q) {
        const int j = tid + (q << 8);
        double dx = pix - (double)pos[3*j];
        double dy = piy - (double)pos[3*j+1];
        double dz = piz - (double)pos[3*j+2];
        double dd = dx*dx + dy*dy + dz*dz;
        d[q] = (j == i) ? INFINITY : dd;
    }

    for (int kk = 0; kk < K; ++kk) {
        // local min over 32 register slots (value, slot)
        double bm = INFINITY; int bq = -1;
        #pragma unroll
        for (int q = 0; q < 32; ++q) {
            if (d[q] < bm) { bm = d[q]; bq = q; }
        }
        int bj = (bq < 0) ? 0x7fffffff : (tid + (bq << 8));

        // 64-lane butterfly reduce, lowest index wins ties
        #pragma unroll
        for (int off = 32; off > 0; off >>= 1) {
            double od = __shfl_xor(bm, off);
            int    oi = __shfl_xor(bj, off);
            if (od < bm || (od == bm && oi < bj)) { bm = od; bj = oi; }
        }
        const int w = tid >> 6;
        if ((tid & 63) == 0) { wmin[w] = bm; wmini[w] = bj; }
        __syncthreads();

        // every thread derives the block winner (deterministic)
        double gm = wmin[0]; int gj = wmini[0];
        #pragma unroll
        for (int q = 1; q < 4; ++q) {
            if (wmin[q] < gm || (wmin[q] == gm && wmini[q] < gj)) { gm = wmin[q]; gj = wmini[q]; }
        }
        if (tid == 0) idx_out[i*K + kk] = gj;

        // remove winner from its owner's register file (static indexing only)
        #pragma unroll
        for (int q = 0; q < 32; ++q) {
            if (tid + (q << 8) == gj) d[q] = INFINITY;
        }
        __syncthreads();   // protect wmin/wmini before next round overwrites
    }
}

// ---------------- Kernel 2: a_dst = x@w_dst, a_src = x@w_src, v = x@w_lin + b ----------------
__global__ __launch_bounds__(192) void lin3_kernel(const float* __restrict__ x,
    const float* __restrict__ w_src, const float* __restrict__ w_dst,
    const float* __restrict__ w_lin, const float* __restrict__ b_lin,
    float* __restrict__ a_dst, float* __restrict__ a_src, float* __restrict__ v) {
    __shared__ float xr[C];
    const int i = blockIdx.x;
    const int tid = threadIdx.x;
    if (tid < C) xr[tid] = x[i*C + tid];
    __syncthreads();
    const int cc = tid & 63;
    const int m  = tid >> 6;
    const float* w = (m == 0) ? w_dst : (m == 1) ? w_src : w_lin;
    float acc = (m == 2) ? b_lin[cc] : 0.0f;
    #pragma unroll 8
    for (int k = 0; k < C; ++k) acc += xr[k] * w[k*C + cc];
    float* o = (m == 0) ? a_dst : (m == 1) ? a_src : v;
    o[i*C + cc] = acc;
}

// ---------------- Kernel 3: per-node edge MLPs + softmax + aggregation + linear_up + residual ----
__global__ __launch_bounds__(256) void edge_kernel(
    const float* __restrict__ x, const float* __restrict__ pos,
    const int* __restrict__ nidx,
    const float* __restrict__ a_dst, const float* __restrict__ a_src, const float* __restrict__ v,
    const float* __restrict__ p1w, const float* __restrict__ p1b,
    const float* __restrict__ p1g, const float* __restrict__ p1bt,
    const float* __restrict__ p2w, const float* __restrict__ p2b,
    const float* __restrict__ a1w, const float* __restrict__ a1b,
    const float* __restrict__ a1g, const float* __restrict__ a1bt,
    const float* __restrict__ a2w, const float* __restrict__ a2b,
    const float* __restrict__ uw, const float* __restrict__ ub,
    float* __restrict__ out) {

    __shared__ float w_p2[C*C], w_a1[C*C], w_a2[C*C], w_uw[C*C]; // 64 KB
    __shared__ float buf1[K][C], buf2[K][C], buf3[K][C];          // 12 KB
    __shared__ float rel[K][4];
    __shared__ int   lidx[K];
    __shared__ float psum[4][C], posum[4][C];
    __shared__ float tmp[C];

    const int i   = blockIdx.x;
    const int tid = threadIdx.x;
    const int c   = tid & 63;
    const int kg  = tid >> 6;

    // stage the four 64x64 weight matrices into LDS (float4, coalesced)
    {
        const float4* s0 = (const float4*)p2w;  float4* d0 = (float4*)w_p2;
        const float4* s1 = (const float4*)a1w;  float4* d1 = (float4*)w_a1;
        const float4* s2 = (const float4*)a2w;  float4* d2 = (float4*)w_a2;
        const float4* s3 = (const float4*)uw;   float4* d3 = (float4*)w_uw;
        for (int q = tid; q < C*C/4; q += 256) {
            d0[q] = s0[q]; d1[q] = s1[q]; d2[q] = s2[q]; d3[q] = s3[q];
        }
    }
    if (tid < K) {
        int j = nidx[i*K + tid];
        lidx[tid] = j;
        rel[tid][0] = pos[3*i]   - pos[3*j];
        rel[tid][1] = pos[3*i+1] - pos[3*j+1];
        rel[tid][2] = pos[3*i+2] - pos[3*j+2];
    }

    // per-channel params in registers (this thread owns channel c)
    const float p1w0 = p1w[c], p1w1 = p1w[C + c], p1w2 = p1w[2*C + c];
    const float p1b_c = p1b[c], p1g_c = p1g[c], p1bt_c = p1bt[c];
    const float p2b_c = p2b[c];
    const float a1b_c = a1b[c], a1g_c = a1g[c], a1bt_c = a1bt[c];
    const float a2b_c = a2b[c];
    const float ub_c  = ub[c];
    const float adst_c = a_dst[i*C + c];

    __syncthreads();

    // h1 = relu(g*(rel@p1w + b) + bt)
    #pragma unroll
    for (int q = 0; q < 4; ++q) {
        const int k = kg + 4*q;
        float h = rel[k][0]*p1w0 + rel[k][1]*p1w1 + rel[k][2]*p1w2 + p1b_c;
        h = p1g_c*h + p1bt_c;
        buf1[k][c] = fmaxf(h, 0.0f);
    }
    __syncthreads();

    // delta = h1@p2w + p2b ; t = a_dst - a_src[j] + delta
    #pragma unroll
    for (int q = 0; q < 4; ++q) {
        const int k = kg + 4*q;
        float acc = p2b_c;
        #pragma unroll 8
        for (int e = 0; e < C; ++e) acc += buf1[k][e] * w_p2[e*C + c];
        buf2[k][c] = acc;
        buf3[k][c] = adst_c - a_src[lidx[k]*C + c] + acc;
    }
    __syncthreads();

    // h2 = relu(g*(t@a1w + b) + bt)   (buf1 reused, old contents consumed)
    #pragma unroll
    for (int q = 0; q < 4; ++q) {
        const int k = kg + 4*q;
        float acc = a1b_c;
        #pragma unroll 8
        for (int e = 0; e < C; ++e) acc += buf3[k][e] * w_a1[e*C + c];
        acc = a1g_c*acc + a1bt_c;
        buf1[k][c] = fmaxf(acc, 0.0f);
    }
    __syncthreads();

    // alpha = h2@a2w + a2b  -> buf3 (t consumed)
    #pragma unroll
    for (int q = 0; q < 4; ++q) {
        const int k = kg + 4*q;
        float acc = a2b_c;
        #pragma unroll 8
        for (int e = 0; e < C; ++e) acc += buf1[k][e] * w_a2[e*C + c];
        buf3[k][c] = acc;
    }
    __syncthreads();

    // softmax over k per channel + weighted aggregation of (v[j] + delta)
    float m = -INFINITY;
    #pragma unroll
    for (int k = 0; k < K; ++k) m = fmaxf(m, buf3[k][c]);
    float ps = 0.0f, po = 0.0f;
    #pragma unroll
    for (int q = 0; q < 4; ++q) {
        const int k = kg + 4*q;
        float e = __expf(buf3[k][c] - m);
        ps += e;
        po += e * (v[lidx[k]*C + c] + buf2[k][c]);
    }
    psum[kg][c] = ps; posum[kg][c] = po;
    __syncthreads();
    if (kg == 0) {
        float s = psum[0][c] + psum[1][c] + psum[2][c] + psum[3][c];
        float o = posum[0][c] + posum[1][c] + posum[2][c] + posum[3][c];
        tmp[c] = o / s;
    }
    __syncthreads();

    // fused epilogue: out = tmp@uw + ub + x
    float facc = ub_c + x[i*C + c];
    #pragma unroll 8
    for (int e = 0; e < C; ++e) facc += tmp[e] * w_uw[e*C + c];
    if (kg == 0) out[i*C + c] = facc;
}

extern "C" void kernel_launch(void* const* d_in, const int* in_sizes, int n_in,
                              void* d_out, int out_size, void* d_ws, size_t ws_size,
                              hipStream_t stream) {
    const float* x     = (const float*)d_in[0];
    const float* pos   = (const float*)d_in[1];
    const float* w_src = (const float*)d_in[2];
    const float* w_dst = (const float*)d_in[3];
    const float* w_lin = (const float*)d_in[4];
    const float* b_lin = (const float*)d_in[5];
    const float* p1w   = (const float*)d_in[6];
    const float* p1b   = (const float*)d_in[7];
    const float* p1g   = (const float*)d_in[8];
    const float* p1bt  = (const float*)d_in[9];
    const float* p2w   = (const float*)d_in[10];
    const float* p2b   = (const float*)d_in[11];
    const float* a1w   = (const float*)d_in[12];
    const float* a1b   = (const float*)d_in[13];
    const float* a1g   = (const float*)d_in[14];
    const float* a1bt  = (const float*)d_in[15];
    const float* a2w   = (const float*)d_in[16];
    const float* a2b   = (const float*)d_in[17];
    const float* uw    = (const float*)d_in[18];
    const float* ub    = (const float*)d_in[19];
    float* out = (float*)d_out;

    char* ws   = (char*)d_ws;
    int*   idx  = (int*)ws;                              // N*K ints
    float* adst = (float*)(ws + (size_t)N*K*sizeof(int));
    float* asrc = adst + (size_t)N*C;
    float* vv   = asrc + (size_t)N*C;

    knn_kernel <<<N, 256, 0, stream>>>(pos, idx);
    lin3_kernel<<<N, 192, 0, stream>>>(x, w_src, w_dst, w_lin, b_lin, adst, asrc, vv);
    edge_kernel<<<N, 256, 0, stream>>>(x, pos, idx, adst, asrc, vv,
        p1w, p1b, p1g, p1bt, p2w, p2b, a1w, a1b, a1g, a1bt, a2w, a2b, uw, ub, out);
}

// Round 3
// 352.904 us; speedup vs baseline: 1.4714x; 1.4714x over previous
//
#include <hip/hip_runtime.h>
#include <math.h>

#define N 8192
#define C 64
#define K 16

typedef unsigned long long u64;
typedef unsigned int u32;

// ---------------- prep: pack pos into float4 for coalesced single-load streaming -------------
__global__ __launch_bounds__(256) void prep_pos4(const float* __restrict__ pos,
                                                 float4* __restrict__ pos4) {
    int j = blockIdx.x * 256 + threadIdx.x;
    if (j < N) pos4[j] = make_float4(pos[3*j], pos[3*j+1], pos[3*j+2], 0.0f);
}

// ---------------- Kernel 1: KNN, wave-per-query streaming top-K ----------------
// Wave w of each block owns query i = blockIdx*4 + w. Lane streams 128 candidates once,
// keeps sorted top-5 packed keys (f32 dist bits | idx) + min-evicted key. 16 rounds of
// 64-lane butterfly argmin merge. Always-on verification (count + f32-error band + truncation
// check); rare exact-f64 fallback in LDS. No __syncthreads in the hot path.
__global__ __launch_bounds__(256) void knn_kernel(const float4* __restrict__ pos4,
                                                  const float* __restrict__ pos,
                                                  int* __restrict__ idx_out) {
    __shared__ int s_cnt[4];
    __shared__ int s_buf[4][256];

    const int tid  = threadIdx.x;
    const int w    = tid >> 6;
    const int lane = tid & 63;
    const int i    = blockIdx.x * 4 + w;

    if (tid < 4) s_cnt[tid] = 0;
    __syncthreads();                      // before any divergence; rare path needs s_cnt=0

    const float4 pi = pos4[i];

    // ---- stream: per-lane sorted top-5 + evicted-min ----
    u64 l0=~0ULL, l1=~0ULL, l2=~0ULL, l3=~0ULL, l4=~0ULL, ev=~0ULL;
    for (int s = 0; s < 128; ++s) {
        const int j = (s << 6) | lane;
        const float4 pj = pos4[j];
        const float dx = pi.x - pj.x, dy = pi.y - pj.y, dz = pi.z - pj.z;
        const float d  = fmaf(dx, dx, fmaf(dy, dy, dz * dz));
        u64 k = ((u64)__float_as_uint(d) << 32) | (u32)j;
        if (j == i) k = ~0ULL;
        const bool ins = k < l4;
        const u64 outk = ins ? l4 : k;
        ev = outk < ev ? outk : ev;
        if (ins) {
            const bool b3 = k < l3, b2 = k < l2, b1 = k < l1, b0 = k < l0;
            l4 = b3 ? l3 : k;
            l3 = b3 ? (b2 ? l2 : k) : l3;
            l2 = b2 ? (b1 ? l1 : k) : l2;
            l1 = b1 ? (b0 ? l0 : k) : l1;
            l0 = b0 ? k : l0;
        }
    }

    // ---- merge: 16 rounds of wave argmin over list heads ----
    int myj = -1;
    u64 keyT = 0;
    for (int kk = 0; kk < K; ++kk) {
        u64 m = l0;
        #pragma unroll
        for (int off = 32; off; off >>= 1) {
            const u64 o = __shfl_xor(m, off, 64);
            m = o < m ? o : m;
        }
        if (l0 == m) { l0 = l1; l1 = l2; l2 = l3; l3 = l4; l4 = ~0ULL; }  // pop (unique key)
        if (lane == kk) myj = (int)(u32)(m & 0xffffffffu);
        keyT = m;                                   // ascending; last = 16th
    }
    if (lane < K) idx_out[i*K + lane] = myj;

    // ---- verification re-stream (always on) ----
    const float dT   = __uint_as_float((u32)(keyT >> 32));
    const float band = 4e-6f * dT + 1e-12f;
    int cnt_le = 0, cnt_band = 0;
    for (int s = 0; s < 128; ++s) {
        const int j = (s << 6) | lane;
        const float4 pj = pos4[j];
        const float dx = pi.x - pj.x, dy = pi.y - pj.y, dz = pi.z - pj.z;
        const float d  = fmaf(dx, dx, fmaf(dy, dy, dz * dz));
        u64 k = ((u64)__float_as_uint(d) << 32) | (u32)j;
        if (j == i) k = ~0ULL;
        cnt_le   += (k <= keyT) ? 1 : 0;
        cnt_band += ((j != i) && (k != keyT) && (fabsf(d - dT) <= band)) ? 1 : 0;
    }
    int packed = cnt_le + (cnt_band << 16);
    #pragma unroll
    for (int off = 32; off; off >>= 1) packed += __shfl_xor(packed, off, 64);
    cnt_le   = packed & 0xffff;
    cnt_band = packed >> 16;
    const bool ok = (cnt_le == K) && (cnt_band == 0) && __all(ev > keyT);

    // ---- rare exact path: collect superset, lane 0 re-selects by (f64 dist, idx) ----
    if (!ok) {
        for (int s = 0; s < 128; ++s) {
            const int j = (s << 6) | lane;
            const float4 pj = pos4[j];
            const float dx = pi.x - pj.x, dy = pi.y - pj.y, dz = pi.z - pj.z;
            const float d  = fmaf(dx, dx, fmaf(dy, dy, dz * dz));
            u64 k = ((u64)__float_as_uint(d) << 32) | (u32)j;
            const bool keep = (j != i) && ((k <= keyT) || (fabsf(d - dT) <= band));
            if (keep) {
                const int slot = atomicAdd(&s_cnt[w], 1);
                if (slot < 256) s_buf[w][slot] = j;
            }
        }
        if (lane == 0) {
            const int cnt = s_cnt[w] < 256 ? s_cnt[w] : 256;
            const double qx = (double)pos[3*i], qy = (double)pos[3*i+1], qz = (double)pos[3*i+2];
            for (int kk = 0; kk < K; ++kk) {
                double bd = 1e300; int bj = 0x7fffffff; int bs = -1;
                for (int e = 0; e < cnt; ++e) {
                    const int j = s_buf[w][e];
                    if (j < 0) continue;
                    const double dx = qx - (double)pos[3*j];
                    const double dy = qy - (double)pos[3*j+1];
                    const double dz = qz - (double)pos[3*j+2];
                    const double dd = dx*dx + dy*dy + dz*dz;
                    if (dd < bd || (dd == bd && j < bj)) { bd = dd; bj = j; bs = e; }
                }
                idx_out[i*K + kk] = bj;
                if (bs >= 0) s_buf[w][bs] = -1;
            }
        }
    }
}

// ---------------- Kernel 2: a_dst = x@w_dst, a_src = x@w_src, v = x@w_lin + b ----------------
__global__ __launch_bounds__(192) void lin3_kernel(const float* __restrict__ x,
    const float* __restrict__ w_src, const float* __restrict__ w_dst,
    const float* __restrict__ w_lin, const float* __restrict__ b_lin,
    float* __restrict__ a_dst, float* __restrict__ a_src, float* __restrict__ v) {
    __shared__ float xr[C];
    const int i = blockIdx.x;
    const int tid = threadIdx.x;
    if (tid < C) xr[tid] = x[i*C + tid];
    __syncthreads();
    const int cc = tid & 63;
    const int m  = tid >> 6;
    const float* w = (m == 0) ? w_dst : (m == 1) ? w_src : w_lin;
    float acc = (m == 2) ? b_lin[cc] : 0.0f;
    #pragma unroll 8
    for (int k = 0; k < C; ++k) acc += xr[k] * w[k*C + cc];
    float* o = (m == 0) ? a_dst : (m == 1) ? a_src : v;
    o[i*C + cc] = acc;
}

// ---------------- Kernel 3: per-node edge MLPs + softmax + aggregation + linear_up + residual ----
__global__ __launch_bounds__(256) void edge_kernel(
    const float* __restrict__ x, const float* __restrict__ pos,
    const int* __restrict__ nidx,
    const float* __restrict__ a_dst, const float* __restrict__ a_src, const float* __restrict__ v,
    const float* __restrict__ p1w, const float* __restrict__ p1b,
    const float* __restrict__ p1g, const float* __restrict__ p1bt,
    const float* __restrict__ p2w, const float* __restrict__ p2b,
    const float* __restrict__ a1w, const float* __restrict__ a1b,
    const float* __restrict__ a1g, const float* __restrict__ a1bt,
    const float* __restrict__ a2w, const float* __restrict__ a2b,
    const float* __restrict__ uw, const float* __restrict__ ub,
    float* __restrict__ out) {

    __shared__ float w_p2[C*C], w_a1[C*C], w_a2[C*C], w_uw[C*C]; // 64 KB
    __shared__ float buf1[K][C], buf2[K][C], buf3[K][C];          // 12 KB
    __shared__ float rel[K][4];
    __shared__ int   lidx[K];
    __shared__ float psum[4][C], posum[4][C];
    __shared__ float tmp[C];

    const int i   = blockIdx.x;
    const int tid = threadIdx.x;
    const int c   = tid & 63;
    const int kg  = tid >> 6;

    {
        const float4* s0 = (const float4*)p2w;  float4* d0 = (float4*)w_p2;
        const float4* s1 = (const float4*)a1w;  float4* d1 = (float4*)w_a1;
        const float4* s2 = (const float4*)a2w;  float4* d2 = (float4*)w_a2;
        const float4* s3 = (const float4*)uw;   float4* d3 = (float4*)w_uw;
        for (int q = tid; q < C*C/4; q += 256) {
            d0[q] = s0[q]; d1[q] = s1[q]; d2[q] = s2[q]; d3[q] = s3[q];
        }
    }
    if (tid < K) {
        int j = nidx[i*K + tid];
        lidx[tid] = j;
        rel[tid][0] = pos[3*i]   - pos[3*j];
        rel[tid][1] = pos[3*i+1] - pos[3*j+1];
        rel[tid][2] = pos[3*i+2] - pos[3*j+2];
    }

    const float p1w0 = p1w[c], p1w1 = p1w[C + c], p1w2 = p1w[2*C + c];
    const float p1b_c = p1b[c], p1g_c = p1g[c], p1bt_c = p1bt[c];
    const float p2b_c = p2b[c];
    const float a1b_c = a1b[c], a1g_c = a1g[c], a1bt_c = a1bt[c];
    const float a2b_c = a2b[c];
    const float ub_c  = ub[c];
    const float adst_c = a_dst[i*C + c];

    __syncthreads();

    #pragma unroll
    for (int q = 0; q < 4; ++q) {
        const int k = kg + 4*q;
        float h = rel[k][0]*p1w0 + rel[k][1]*p1w1 + rel[k][2]*p1w2 + p1b_c;
        h = p1g_c*h + p1bt_c;
        buf1[k][c] = fmaxf(h, 0.0f);
    }
    __syncthreads();

    #pragma unroll
    for (int q = 0; q < 4; ++q) {
        const int k = kg + 4*q;
        float acc = p2b_c;
        #pragma unroll 8
        for (int e = 0; e < C; ++e) acc += buf1[k][e] * w_p2[e*C + c];
        buf2[k][c] = acc;
        buf3[k][c] = adst_c - a_src[lidx[k]*C + c] + acc;
    }
    __syncthreads();

    #pragma unroll
    for (int q = 0; q < 4; ++q) {
        const int k = kg + 4*q;
        float acc = a1b_c;
        #pragma unroll 8
        for (int e = 0; e < C; ++e) acc += buf3[k][e] * w_a1[e*C + c];
        acc = a1g_c*acc + a1bt_c;
        buf1[k][c] = fmaxf(acc, 0.0f);
    }
    __syncthreads();

    #pragma unroll
    for (int q = 0; q < 4; ++q) {
        const int k = kg + 4*q;
        float acc = a2b_c;
        #pragma unroll 8
        for (int e = 0; e < C; ++e) acc += buf1[k][e] * w_a2[e*C + c];
        buf3[k][c] = acc;
    }
    __syncthreads();

    float m = -INFINITY;
    #pragma unroll
    for (int k = 0; k < K; ++k) m = fmaxf(m, buf3[k][c]);
    float ps = 0.0f, po = 0.0f;
    #pragma unroll
    for (int q = 0; q < 4; ++q) {
        const int k = kg + 4*q;
        float e = __expf(buf3[k][c] - m);
        ps += e;
        po += e * (v[lidx[k]*C + c] + buf2[k][c]);
    }
    psum[kg][c] = ps; posum[kg][c] = po;
    __syncthreads();
    if (kg == 0) {
        float s = psum[0][c] + psum[1][c] + psum[2][c] + psum[3][c];
        float o = posum[0][c] + posum[1][c] + posum[2][c] + posum[3][c];
        tmp[c] = o / s;
    }
    __syncthreads();

    float facc = ub_c + x[i*C + c];
    #pragma unroll 8
    for (int e = 0; e < C; ++e) facc += tmp[e] * w_uw[e*C + c];
    if (kg == 0) out[i*C + c] = facc;
}

extern "C" void kernel_launch(void* const* d_in, const int* in_sizes, int n_in,
                              void* d_out, int out_size, void* d_ws, size_t ws_size,
                              hipStream_t stream) {
    const float* x     = (const float*)d_in[0];
    const float* pos   = (const float*)d_in[1];
    const float* w_src = (const float*)d_in[2];
    const float* w_dst = (const float*)d_in[3];
    const float* w_lin = (const float*)d_in[4];
    const float* b_lin = (const float*)d_in[5];
    const float* p1w   = (const float*)d_in[6];
    const float* p1b   = (const float*)d_in[7];
    const float* p1g   = (const float*)d_in[8];
    const float* p1bt  = (const float*)d_in[9];
    const float* p2w   = (const float*)d_in[10];
    const float* p2b   = (const float*)d_in[11];
    const float* a1w   = (const float*)d_in[12];
    const float* a1b   = (const float*)d_in[13];
    const float* a1g   = (const float*)d_in[14];
    const float* a1bt  = (const float*)d_in[15];
    const float* a2w   = (const float*)d_in[16];
    const float* a2b   = (const float*)d_in[17];
    const float* uw    = (const float*)d_in[18];
    const float* ub    = (const float*)d_in[19];
    float* out = (float*)d_out;

    char* ws    = (char*)d_ws;
    int*    idx  = (int*)ws;                                    // N*K ints
    float*  adst = (float*)(ws + (size_t)N*K*sizeof(int));
    float*  asrc = adst + (size_t)N*C;
    float*  vv   = asrc + (size_t)N*C;
    float4* pos4 = (float4*)(vv + (size_t)N*C);                 // N float4

    prep_pos4 <<<(N + 255)/256, 256, 0, stream>>>(pos, pos4);
    knn_kernel<<<N/4, 256, 0, stream>>>(pos4, pos, idx);
    lin3_kernel<<<N, 192, 0, stream>>>(x, w_src, w_dst, w_lin, b_lin, adst, asrc, vv);
    edge_kernel<<<N, 256, 0, stream>>>(x, pos, idx, adst, asrc, vv,
        p1w, p1b, p1g, p1bt, p2w, p2b, a1w, a1b, a1g, a1bt, a2w, a2b, uw, ub, out);
}

// Round 4
// 220.047 us; speedup vs baseline: 2.3598x; 1.6038x over previous
//
#include <hip/hip_runtime.h>
#include <math.h>

#define N 8192
#define C 64
#define K 16
#define NB 8

typedef unsigned long long u64;
typedef unsigned int u32;

// ---------------- prep: pack pos into float4 ----------------
__global__ __launch_bounds__(256) void prep_pos4(const float* __restrict__ pos,
                                                 float4* __restrict__ pos4) {
    int j = blockIdx.x * 256 + threadIdx.x;
    if (j < N) pos4[j] = make_float4(pos[3*j], pos[3*j+1], pos[3*j+2], 0.0f);
}

// ---------------- Kernel 1: KNN, wave-per-query streaming top-K (unchanged, verified) --------
__global__ __launch_bounds__(256) void knn_kernel(const float4* __restrict__ pos4,
                                                  const float* __restrict__ pos,
                                                  int* __restrict__ idx_out) {
    __shared__ int s_cnt[4];
    __shared__ int s_buf[4][256];

    const int tid  = threadIdx.x;
    const int w    = tid >> 6;
    const int lane = tid & 63;
    const int i    = blockIdx.x * 4 + w;

    if (tid < 4) s_cnt[tid] = 0;
    __syncthreads();

    const float4 pi = pos4[i];

    u64 l0=~0ULL, l1=~0ULL, l2=~0ULL, l3=~0ULL, l4=~0ULL, ev=~0ULL;
    for (int s = 0; s < 128; ++s) {
        const int j = (s << 6) | lane;
        const float4 pj = pos4[j];
        const float dx = pi.x - pj.x, dy = pi.y - pj.y, dz = pi.z - pj.z;
        const float d  = fmaf(dx, dx, fmaf(dy, dy, dz * dz));
        u64 k = ((u64)__float_as_uint(d) << 32) | (u32)j;
        if (j == i) k = ~0ULL;
        const bool ins = k < l4;
        const u64 outk = ins ? l4 : k;
        ev = outk < ev ? outk : ev;
        if (ins) {
            const bool b3 = k < l3, b2 = k < l2, b1 = k < l1, b0 = k < l0;
            l4 = b3 ? l3 : k;
            l3 = b3 ? (b2 ? l2 : k) : l3;
            l2 = b2 ? (b1 ? l1 : k) : l2;
            l1 = b1 ? (b0 ? l0 : k) : l1;
            l0 = b0 ? k : l0;
        }
    }

    int myj = -1;
    u64 keyT = 0;
    for (int kk = 0; kk < K; ++kk) {
        u64 m = l0;
        #pragma unroll
        for (int off = 32; off; off >>= 1) {
            const u64 o = __shfl_xor(m, off, 64);
            m = o < m ? o : m;
        }
        if (l0 == m) { l0 = l1; l1 = l2; l2 = l3; l3 = l4; l4 = ~0ULL; }
        if (lane == kk) myj = (int)(u32)(m & 0xffffffffu);
        keyT = m;
    }
    if (lane < K) idx_out[i*K + lane] = myj;

    const float dT   = __uint_as_float((u32)(keyT >> 32));
    const float band = 4e-6f * dT + 1e-12f;
    int cnt_le = 0, cnt_band = 0;
    for (int s = 0; s < 128; ++s) {
        const int j = (s << 6) | lane;
        const float4 pj = pos4[j];
        const float dx = pi.x - pj.x, dy = pi.y - pj.y, dz = pi.z - pj.z;
        const float d  = fmaf(dx, dx, fmaf(dy, dy, dz * dz));
        u64 k = ((u64)__float_as_uint(d) << 32) | (u32)j;
        if (j == i) k = ~0ULL;
        cnt_le   += (k <= keyT) ? 1 : 0;
        cnt_band += ((j != i) && (k != keyT) && (fabsf(d - dT) <= band)) ? 1 : 0;
    }
    int packed = cnt_le + (cnt_band << 16);
    #pragma unroll
    for (int off = 32; off; off >>= 1) packed += __shfl_xor(packed, off, 64);
    cnt_le   = packed & 0xffff;
    cnt_band = packed >> 16;
    const bool ok = (cnt_le == K) && (cnt_band == 0) && __all(ev > keyT);

    if (!ok) {
        for (int s = 0; s < 128; ++s) {
            const int j = (s << 6) | lane;
            const float4 pj = pos4[j];
            const float dx = pi.x - pj.x, dy = pi.y - pj.y, dz = pi.z - pj.z;
            const float d  = fmaf(dx, dx, fmaf(dy, dy, dz * dz));
            u64 k = ((u64)__float_as_uint(d) << 32) | (u32)j;
            const bool keep = (j != i) && ((k <= keyT) || (fabsf(d - dT) <= band));
            if (keep) {
                const int slot = atomicAdd(&s_cnt[w], 1);
                if (slot < 256) s_buf[w][slot] = j;
            }
        }
        if (lane == 0) {
            const int cnt = s_cnt[w] < 256 ? s_cnt[w] : 256;
            const double qx = (double)pos[3*i], qy = (double)pos[3*i+1], qz = (double)pos[3*i+2];
            for (int kk = 0; kk < K; ++kk) {
                double bd = 1e300; int bj = 0x7fffffff; int bs = -1;
                for (int e = 0; e < cnt; ++e) {
                    const int j = s_buf[w][e];
                    if (j < 0) continue;
                    const double dx = qx - (double)pos[3*j];
                    const double dy = qy - (double)pos[3*j+1];
                    const double dz = qz - (double)pos[3*j+2];
                    const double dd = dx*dx + dy*dy + dz*dz;
                    if (dd < bd || (dd == bd && j < bj)) { bd = dd; bj = j; bs = e; }
                }
                idx_out[i*K + kk] = bj;
                if (bs >= 0) s_buf[w][bs] = -1;
            }
        }
    }
}

// ---------------- Kernel 2: a_dst/a_src/v projections (unchanged) ----------------
__global__ __launch_bounds__(192) void lin3_kernel(const float* __restrict__ x,
    const float* __restrict__ w_src, const float* __restrict__ w_dst,
    const float* __restrict__ w_lin, const float* __restrict__ b_lin,
    float* __restrict__ a_dst, float* __restrict__ a_src, float* __restrict__ v) {
    __shared__ float xr[C];
    const int i = blockIdx.x;
    const int tid = threadIdx.x;
    if (tid < C) xr[tid] = x[i*C + tid];
    __syncthreads();
    const int cc = tid & 63;
    const int m  = tid >> 6;
    const float* w = (m == 0) ? w_dst : (m == 1) ? w_src : w_lin;
    float acc = (m == 2) ? b_lin[cc] : 0.0f;
    #pragma unroll 8
    for (int k = 0; k < C; ++k) acc += xr[k] * w[k*C + cc];
    float* o = (m == 0) ? a_dst : (m == 1) ? a_src : v;
    o[i*C + cc] = acc;
}

// ---------------- Kernel 3: edge pipeline, wave-per-node, register-resident K ----------------
// 512 thr = 8 waves = 8 nodes. Thread (node w, channel c) keeps all 16 edge values in regs.
// Per-node H tile [64 chan][16 k] in LDS is WAVE-PRIVATE (no barriers). Weights staged one
// matrix at a time (16 KB, the only barrier source). Softmax is a per-thread 16-reg reduce.
__global__ __launch_bounds__(512, 4) void edge_kernel(
    const float* __restrict__ x, const float* __restrict__ pos,
    const int* __restrict__ nidx,
    const float* __restrict__ a_dst, const float* __restrict__ a_src, const float* __restrict__ v,
    const float* __restrict__ p1w, const float* __restrict__ p1b,
    const float* __restrict__ p1g, const float* __restrict__ p1bt,
    const float* __restrict__ p2w, const float* __restrict__ p2b,
    const float* __restrict__ a1w, const float* __restrict__ a1b,
    const float* __restrict__ a1g, const float* __restrict__ a1bt,
    const float* __restrict__ a2w, const float* __restrict__ a2b,
    const float* __restrict__ uw, const float* __restrict__ ub,
    float* __restrict__ out) {

    __shared__ float  wbuf[C*C];        // 16 KB: current-phase weight matrix [e][c]
    __shared__ float  sH[NB*C*K];       // 32 KB: per-node [chan e][edge k]
    __shared__ float4 sMisc4[NB*16];    // 2 KB: rel (16 x float4) then agg[64]
    __shared__ int    sIdx[NB*K];       // 512 B

    const int tid = threadIdx.x;
    const int w   = tid >> 6;
    const int c   = tid & 63;
    const int n   = blockIdx.x * NB + w;

    float*  Hl  = sH + w * (C*K);
    float4* Ml4 = sMisc4 + w * 16;
    float*  Mlf = (float*)Ml4;
    int*    Il  = sIdx + w * K;

    // stage wbuf <- p2w (phase-1 below doesn't touch wbuf, overlaps latency)
    {
        const float4* s = (const float4*)p2w;
        float4* d = (float4*)wbuf;
        d[tid] = s[tid];
        d[tid + 512] = s[tid + 512];
    }
    // neighbor ids + rel vectors (lane<16 of each wave; wave-private, in-order LDS)
    if (c < K) {
        int j = nidx[n*K + c];
        Il[c] = j;
        float4 r;
        r.x = pos[3*n]   - pos[3*j];
        r.y = pos[3*n+1] - pos[3*j+1];
        r.z = pos[3*n+2] - pos[3*j+2];
        r.w = 0.0f;
        Ml4[c] = r;
    }

    // per-channel params
    const float p1w0 = p1w[c], p1w1 = p1w[C + c], p1w2 = p1w[2*C + c];
    const float p1b_c = p1b[c], p1g_c = p1g[c], p1bt_c = p1bt[c];
    const float p2b_c = p2b[c];
    const float a1b_c = a1b[c], a1g_c = a1g[c], a1bt_c = a1bt[c];
    const float a2b_c = a2b[c];
    const float ub_c  = ub[c];
    const float adst_c = a_dst[n*C + c];
    const float x_nc   = x[n*C + c];

    // ---- phase 1: h1 = relu(g*(rel@p1w + b) + bt), write H[c][k] ----
    float h[K];
    #pragma unroll
    for (int k = 0; k < K; ++k) {
        float4 r = Ml4[k];                                  // uniform broadcast
        float t = fmaf(r.x, p1w0, fmaf(r.y, p1w1, fmaf(r.z, p1w2, p1b_c)));
        t = fmaf(p1g_c, t, p1bt_c);
        h[k] = fmaxf(t, 0.0f);
    }
    float4* Hw = (float4*)(Hl + c*K);
    Hw[0] = make_float4(h[0], h[1], h[2], h[3]);
    Hw[1] = make_float4(h[4], h[5], h[6], h[7]);
    Hw[2] = make_float4(h[8], h[9], h[10], h[11]);
    Hw[3] = make_float4(h[12], h[13], h[14], h[15]);

    __syncthreads();   // wbuf(p2w) ready

    // prefetch asrc gathers (independent of phase-2 loop)
    float asv[K];
    #pragma unroll
    for (int k = 0; k < K; ++k) asv[k] = a_src[Il[k]*C + c];

    // ---- phase 2: delta[k] = sum_e H[e][k] * p2w[e][c] + p2b ----
    float acc[K];
    #pragma unroll
    for (int k = 0; k < K; ++k) acc[k] = p2b_c;
    #pragma unroll 4
    for (int e = 0; e < C; ++e) {
        const float we = wbuf[e*C + c];
        const float4* A = (const float4*)(Hl + e*K);
        const float4 a0 = A[0], a1 = A[1], a2 = A[2], a3 = A[3];
        acc[0]  = fmaf(a0.x, we, acc[0]);  acc[1]  = fmaf(a0.y, we, acc[1]);
        acc[2]  = fmaf(a0.z, we, acc[2]);  acc[3]  = fmaf(a0.w, we, acc[3]);
        acc[4]  = fmaf(a1.x, we, acc[4]);  acc[5]  = fmaf(a1.y, we, acc[5]);
        acc[6]  = fmaf(a1.z, we, acc[6]);  acc[7]  = fmaf(a1.w, we, acc[7]);
        acc[8]  = fmaf(a2.x, we, acc[8]);  acc[9]  = fmaf(a2.y, we, acc[9]);
        acc[10] = fmaf(a2.z, we, acc[10]); acc[11] = fmaf(a2.w, we, acc[11]);
        acc[12] = fmaf(a3.x, we, acc[12]); acc[13] = fmaf(a3.w == a3.w ? a3.w : a3.w, 0.0f, fmaf(a3.y, we, acc[13]));
        acc[14] = fmaf(a3.z, we, acc[14]); acc[15] = fmaf(a3.w, we, acc[15]);
    }
    float del[K];
    #pragma unroll
    for (int k = 0; k < K; ++k) del[k] = acc[k];

    // t = adst - asrc + delta -> H (own row; all reads of H done — lockstep)
    #pragma unroll
    for (int k = 0; k < K; ++k) h[k] = adst_c - asv[k] + del[k];
    Hw[0] = make_float4(h[0], h[1], h[2], h[3]);
    Hw[1] = make_float4(h[4], h[5], h[6], h[7]);
    Hw[2] = make_float4(h[8], h[9], h[10], h[11]);
    Hw[3] = make_float4(h[12], h[13], h[14], h[15]);

    __syncthreads();   // all done reading wbuf(p2w)
    {
        const float4* s = (const float4*)a1w;
        float4* d = (float4*)wbuf;
        d[tid] = s[tid];
        d[tid + 512] = s[tid + 512];
    }
    __syncthreads();   // wbuf(a1w) ready

    // ---- phase 3: h2 = relu(g*(t@a1w + b) + bt) ----
    #pragma unroll
    for (int k = 0; k < K; ++k) acc[k] = a1b_c;
    #pragma unroll 4
    for (int e = 0; e < C; ++e) {
        const float we = wbuf[e*C + c];
        const float4* A = (const float4*)(Hl + e*K);
        const float4 a0 = A[0], a1 = A[1], a2 = A[2], a3 = A[3];
        acc[0]  = fmaf(a0.x, we, acc[0]);  acc[1]  = fmaf(a0.y, we, acc[1]);
        acc[2]  = fmaf(a0.z, we, acc[2]);  acc[3]  = fmaf(a0.w, we, acc[3]);
        acc[4]  = fmaf(a1.x, we, acc[4]);  acc[5]  = fmaf(a1.y, we, acc[5]);
        acc[6]  = fmaf(a1.z, we, acc[6]);  acc[7]  = fmaf(a1.w, we, acc[7]);
        acc[8]  = fmaf(a2.x, we, acc[8]);  acc[9]  = fmaf(a2.y, we, acc[9]);
        acc[10] = fmaf(a2.z, we, acc[10]); acc[11] = fmaf(a2.w, we, acc[11]);
        acc[12] = fmaf(a3.x, we, acc[12]); acc[13] = fmaf(a3.y, we, acc[13]);
        acc[14] = fmaf(a3.z, we, acc[14]); acc[15] = fmaf(a3.w, we, acc[15]);
    }
    #pragma unroll
    for (int k = 0; k < K; ++k) h[k] = fmaxf(fmaf(a1g_c, acc[k], a1bt_c), 0.0f);
    Hw[0] = make_float4(h[0], h[1], h[2], h[3]);
    Hw[1] = make_float4(h[4], h[5], h[6], h[7]);
    Hw[2] = make_float4(h[8], h[9], h[10], h[11]);
    Hw[3] = make_float4(h[12], h[13], h[14], h[15]);

    __syncthreads();   // done reading wbuf(a1w)
    {
        const float4* s = (const float4*)a2w;
        float4* d = (float4*)wbuf;
        d[tid] = s[tid];
        d[tid + 512] = s[tid + 512];
    }
    __syncthreads();   // wbuf(a2w) ready

    // prefetch v gathers
    float vg[K];
    #pragma unroll
    for (int k = 0; k < K; ++k) vg[k] = v[Il[k]*C + c];

    // ---- phase 4: alpha = h2@a2w + a2b ----
    #pragma unroll
    for (int k = 0; k < K; ++k) acc[k] = a2b_c;
    #pragma unroll 4
    for (int e = 0; e < C; ++e) {
        const float we = wbuf[e*C + c];
        const float4* A = (const float4*)(Hl + e*K);
        const float4 a0 = A[0], a1 = A[1], a2 = A[2], a3 = A[3];
        acc[0]  = fmaf(a0.x, we, acc[0]);  acc[1]  = fmaf(a0.y, we, acc[1]);
        acc[2]  = fmaf(a0.z, we, acc[2]);  acc[3]  = fmaf(a0.w, we, acc[3]);
        acc[4]  = fmaf(a1.x, we, acc[4]);  acc[5]  = fmaf(a1.y, we, acc[5]);
        acc[6]  = fmaf(a1.z, we, acc[6]);  acc[7]  = fmaf(a1.w, we, acc[7]);
        acc[8]  = fmaf(a2.x, we, acc[8]);  acc[9]  = fmaf(a2.y, we, acc[9]);
        acc[10] = fmaf(a2.z, we, acc[10]); acc[11] = fmaf(a2.w, we, acc[11]);
        acc[12] = fmaf(a3.x, we, acc[12]); acc[13] = fmaf(a3.y, we, acc[13]);
        acc[14] = fmaf(a3.z, we, acc[14]); acc[15] = fmaf(a3.w, we, acc[15]);
    }

    // ---- softmax over k (registers) + aggregation ----
    float m = acc[0];
    #pragma unroll
    for (int k = 1; k < K; ++k) m = fmaxf(m, acc[k]);
    float s = 0.0f, ag = 0.0f;
    #pragma unroll
    for (int k = 0; k < K; ++k) {
        float e_ = __expf(acc[k] - m);
        s += e_;
        ag = fmaf(e_, vg[k] + del[k], ag);
    }
    Mlf[c] = ag / s;   // reuse rel region (consumed in phase 1)

    __syncthreads();   // done reading wbuf(a2w)
    {
        const float4* s4 = (const float4*)uw;
        float4* d = (float4*)wbuf;
        d[tid] = s4[tid];
        d[tid + 512] = s4[tid + 512];
    }
    __syncthreads();   // wbuf(uw) ready

    // ---- epilogue: out = agg@uw + ub + x ----
    float facc = ub_c + x_nc;
    #pragma unroll 4
    for (int e4 = 0; e4 < 16; ++e4) {
        const float4 g4 = Ml4[e4];                          // uniform broadcast
        facc = fmaf(g4.x, wbuf[(e4*4+0)*C + c], facc);
        facc = fmaf(g4.y, wbuf[(e4*4+1)*C + c], facc);
        facc = fmaf(g4.z, wbuf[(e4*4+2)*C + c], facc);
        facc = fmaf(g4.w, wbuf[(e4*4+3)*C + c], facc);
    }
    out[n*C + c] = facc;
}

extern "C" void kernel_launch(void* const* d_in, const int* in_sizes, int n_in,
                              void* d_out, int out_size, void* d_ws, size_t ws_size,
                              hipStream_t stream) {
    const float* x     = (const float*)d_in[0];
    const float* pos   = (const float*)d_in[1];
    const float* w_src = (const float*)d_in[2];
    const float* w_dst = (const float*)d_in[3];
    const float* w_lin = (const float*)d_in[4];
    const float* b_lin = (const float*)d_in[5];
    const float* p1w   = (const float*)d_in[6];
    const float* p1b   = (const float*)d_in[7];
    const float* p1g   = (const float*)d_in[8];
    const float* p1bt  = (const float*)d_in[9];
    const float* p2w   = (const float*)d_in[10];
    const float* p2b   = (const float*)d_in[11];
    const float* a1w   = (const float*)d_in[12];
    const float* a1b   = (const float*)d_in[13];
    const float* a1g   = (const float*)d_in[14];
    const float* a1bt  = (const float*)d_in[15];
    const float* a2w   = (const float*)d_in[16];
    const float* a2b   = (const float*)d_in[17];
    const float* uw    = (const float*)d_in[18];
    const float* ub    = (const float*)d_in[19];
    float* out = (float*)d_out;

    char* ws    = (char*)d_ws;
    int*    idx  = (int*)ws;                                    // N*K ints
    float*  adst = (float*)(ws + (size_t)N*K*sizeof(int));
    float*  asrc = adst + (size_t)N*C;
    float*  vv   = asrc + (size_t)N*C;
    float4* pos4 = (float4*)(vv + (size_t)N*C);                 // N float4

    prep_pos4 <<<(N + 255)/256, 256, 0, stream>>>(pos, pos4);
    knn_kernel<<<N/4, 256, 0, stream>>>(pos4, pos, idx);
    lin3_kernel<<<N, 192, 0, stream>>>(x, w_src, w_dst, w_lin, b_lin, adst, asrc, vv);
    edge_kernel<<<N/NB, 512, 0, stream>>>(x, pos, idx, adst, asrc, vv,
        p1w, p1b, p1g, p1bt, p2w, p2b, a1w, a1b, a1g, a1bt, a2w, a2b, uw, ub, out);
}

// Round 5
// 167.165 us; speedup vs baseline: 3.1063x; 1.3163x over previous
//
#include <hip/hip_runtime.h>
#include <math.h>

#define N 8192
#define C 64
#define K 16
#define NB 8

typedef unsigned long long u64;
typedef unsigned int u32;

// ---------------- prep: pack pos into float4 ----------------
__global__ __launch_bounds__(256) void prep_pos4(const float* __restrict__ pos,
                                                 float4* __restrict__ pos4) {
    int j = blockIdx.x * 256 + threadIdx.x;
    if (j < N) pos4[j] = make_float4(pos[3*j], pos[3*j+1], pos[3*j+2], 0.0f);
}

// ---------------- Kernel 1: KNN via threshold filter ----------------
// Wave per query. Pass 1: lane-min over 128 disjoint candidates -> T = 16th smallest of the
// 64 lane minima (disjointness guarantees >=16 candidates with d <= T). Pass 2: ballot-compact
// {d <= T+M} into LDS (M covers f32 rounding; expected ~20 collected). Pass 3: exact
// (f64 dist, idx) all-pairs rank over the collected set -> top-16 written by rank.
__global__ __launch_bounds__(256) void knn_kernel(const float4* __restrict__ pos4,
                                                  int* __restrict__ idx_out) {
    __shared__ int    s_buf[4][256];   // collected candidate ids
    __shared__ double s_d[4][256];     // their f64 distances
    __shared__ double s_fd[4][K];      // fallback top-16 (lane0 serial, unreachable)
    __shared__ int    s_fi[4][K];

    const int tid  = threadIdx.x;
    const int w    = tid >> 6;
    const int lane = tid & 63;
    const int i    = blockIdx.x * 4 + w;

    const float4 pi = pos4[i];

    // ---- pass 1: per-lane min distance ----
    float mn = INFINITY;
    #pragma unroll 4
    for (int s = 0; s < 128; ++s) {
        const int j = (s << 6) | lane;
        const float4 pj = pos4[j];
        const float dx = pi.x - pj.x, dy = pi.y - pj.y, dz = pi.z - pj.z;
        float d = fmaf(dx, dx, fmaf(dy, dy, dz * dz));
        if (j == i) d = INFINITY;
        mn = fminf(mn, d);
    }

    // ---- T = 16th smallest lane-min (u64 evict-min over 64 unique keys) ----
    u64 cur = ((u64)__float_as_uint(mn) << 32) | (u32)lane;
    float T = 0.0f;
    for (int r = 0; r < K; ++r) {
        u64 m = cur;
        #pragma unroll
        for (int off = 32; off; off >>= 1) {
            const u64 o = __shfl_xor(m, off, 64);
            m = o < m ? o : m;
        }
        if (cur == m) cur = ~0ULL;
        T = __uint_as_float((u32)(m >> 32));
    }
    const float thr = T + 1e-5f * (sqrtf(T) + T + 1.0f);   // f32-error margin

    // ---- pass 2: ballot-compact candidates with d <= thr ----
    int cnt = 0;
    #pragma unroll 4
    for (int s = 0; s < 128; ++s) {
        const int j = (s << 6) | lane;
        const float4 pj = pos4[j];
        const float dx = pi.x - pj.x, dy = pi.y - pj.y, dz = pi.z - pj.z;
        const float d  = fmaf(dx, dx, fmaf(dy, dy, dz * dz));
        const bool sel = (j != i) && (d <= thr);
        const u64 mask = __ballot(sel);
        if (sel) {
            const int p = __popcll(mask & ((1ULL << lane) - 1ULL));
            const int slot = cnt + p;
            if (slot < 256) s_buf[w][slot] = j;
        }
        cnt += (int)__popcll(mask);
    }

    if (cnt <= 256) {
        const int cn = cnt;
        const double qx = (double)pi.x, qy = (double)pi.y, qz = (double)pi.z;
        // f64 distances into LDS (wave-private, in-order DS pipe)
        for (int sl = lane; sl < cn; sl += 64) {
            const int j = s_buf[w][sl];
            const float4 pj = pos4[j];
            const double dx = qx - (double)pj.x;
            const double dy = qy - (double)pj.y;
            const double dz = qz - (double)pj.z;
            s_d[w][sl] = dx*dx + dy*dy + dz*dz;
        }
        // all-pairs rank; rank<16 writes its slot
        for (int sl = lane; sl < cn; sl += 64) {
            const int    j  = s_buf[w][sl];
            const double dj = s_d[w][sl];
            int r = 0;
            for (int e = 0; e < cn; ++e) {
                const double de = s_d[w][e];
                const int    je = s_buf[w][e];
                r += (de < dj || (de == dj && je < j)) ? 1 : 0;
            }
            if (r < K) idx_out[i*K + r] = j;
        }
    } else {
        // unreachable safety net: lane0 exact serial top-16 over all N
        if (lane == 0) {
            for (int kk = 0; kk < K; ++kk) { s_fd[w][kk] = 1e300; s_fi[w][kk] = 0x7fffffff; }
            const double qx = (double)pi.x, qy = (double)pi.y, qz = (double)pi.z;
            for (int j = 0; j < N; ++j) {
                if (j == i) continue;
                const float4 pj = pos4[j];
                const double dx = qx - (double)pj.x;
                const double dy = qy - (double)pj.y;
                const double dz = qz - (double)pj.z;
                const double dd = dx*dx + dy*dy + dz*dz;
                if (dd < s_fd[w][K-1] || (dd == s_fd[w][K-1] && j < s_fi[w][K-1])) {
                    int p = K - 1;
                    while (p > 0 && (dd < s_fd[w][p-1] || (dd == s_fd[w][p-1] && j < s_fi[w][p-1]))) {
                        s_fd[w][p] = s_fd[w][p-1]; s_fi[w][p] = s_fi[w][p-1]; --p;
                    }
                    s_fd[w][p] = dd; s_fi[w][p] = j;
                }
            }
            for (int kk = 0; kk < K; ++kk) idx_out[i*K + kk] = s_fi[w][kk];
        }
    }
}

// ---------------- Kernel 2: a_dst/a_src/v projections (unchanged) ----------------
__global__ __launch_bounds__(192) void lin3_kernel(const float* __restrict__ x,
    const float* __restrict__ w_src, const float* __restrict__ w_dst,
    const float* __restrict__ w_lin, const float* __restrict__ b_lin,
    float* __restrict__ a_dst, float* __restrict__ a_src, float* __restrict__ v) {
    __shared__ float xr[C];
    const int i = blockIdx.x;
    const int tid = threadIdx.x;
    if (tid < C) xr[tid] = x[i*C + tid];
    __syncthreads();
    const int cc = tid & 63;
    const int m  = tid >> 6;
    const float* w = (m == 0) ? w_dst : (m == 1) ? w_src : w_lin;
    float acc = (m == 2) ? b_lin[cc] : 0.0f;
    #pragma unroll 8
    for (int k = 0; k < C; ++k) acc += xr[k] * w[k*C + cc];
    float* o = (m == 0) ? a_dst : (m == 1) ? a_src : v;
    o[i*C + cc] = acc;
}

// ---------------- Kernel 3: edge pipeline, wave-per-node, register-resident K (unchanged) ----
__global__ __launch_bounds__(512, 4) void edge_kernel(
    const float* __restrict__ x, const float* __restrict__ pos,
    const int* __restrict__ nidx,
    const float* __restrict__ a_dst, const float* __restrict__ a_src, const float* __restrict__ v,
    const float* __restrict__ p1w, const float* __restrict__ p1b,
    const float* __restrict__ p1g, const float* __restrict__ p1bt,
    const float* __restrict__ p2w, const float* __restrict__ p2b,
    const float* __restrict__ a1w, const float* __restrict__ a1b,
    const float* __restrict__ a1g, const float* __restrict__ a1bt,
    const float* __restrict__ a2w, const float* __restrict__ a2b,
    const float* __restrict__ uw, const float* __restrict__ ub,
    float* __restrict__ out) {

    __shared__ float  wbuf[C*C];
    __shared__ float  sH[NB*C*K];
    __shared__ float4 sMisc4[NB*16];
    __shared__ int    sIdx[NB*K];

    const int tid = threadIdx.x;
    const int w   = tid >> 6;
    const int c   = tid & 63;
    const int n   = blockIdx.x * NB + w;

    float*  Hl  = sH + w * (C*K);
    float4* Ml4 = sMisc4 + w * 16;
    float*  Mlf = (float*)Ml4;
    int*    Il  = sIdx + w * K;

    {
        const float4* s = (const float4*)p2w;
        float4* d = (float4*)wbuf;
        d[tid] = s[tid];
        d[tid + 512] = s[tid + 512];
    }
    if (c < K) {
        int j = nidx[n*K + c];
        Il[c] = j;
        float4 r;
        r.x = pos[3*n]   - pos[3*j];
        r.y = pos[3*n+1] - pos[3*j+1];
        r.z = pos[3*n+2] - pos[3*j+2];
        r.w = 0.0f;
        Ml4[c] = r;
    }

    const float p1w0 = p1w[c], p1w1 = p1w[C + c], p1w2 = p1w[2*C + c];
    const float p1b_c = p1b[c], p1g_c = p1g[c], p1bt_c = p1bt[c];
    const float p2b_c = p2b[c];
    const float a1b_c = a1b[c], a1g_c = a1g[c], a1bt_c = a1bt[c];
    const float a2b_c = a2b[c];
    const float ub_c  = ub[c];
    const float adst_c = a_dst[n*C + c];
    const float x_nc   = x[n*C + c];

    float h[K];
    #pragma unroll
    for (int k = 0; k < K; ++k) {
        float4 r = Ml4[k];
        float t = fmaf(r.x, p1w0, fmaf(r.y, p1w1, fmaf(r.z, p1w2, p1b_c)));
        t = fmaf(p1g_c, t, p1bt_c);
        h[k] = fmaxf(t, 0.0f);
    }
    float4* Hw = (float4*)(Hl + c*K);
    Hw[0] = make_float4(h[0], h[1], h[2], h[3]);
    Hw[1] = make_float4(h[4], h[5], h[6], h[7]);
    Hw[2] = make_float4(h[8], h[9], h[10], h[11]);
    Hw[3] = make_float4(h[12], h[13], h[14], h[15]);

    __syncthreads();

    float asv[K];
    #pragma unroll
    for (int k = 0; k < K; ++k) asv[k] = a_src[Il[k]*C + c];

    float acc[K];
    #pragma unroll
    for (int k = 0; k < K; ++k) acc[k] = p2b_c;
    #pragma unroll 4
    for (int e = 0; e < C; ++e) {
        const float we = wbuf[e*C + c];
        const float4* A = (const float4*)(Hl + e*K);
        const float4 a0 = A[0], a1 = A[1], a2 = A[2], a3 = A[3];
        acc[0]  = fmaf(a0.x, we, acc[0]);  acc[1]  = fmaf(a0.y, we, acc[1]);
        acc[2]  = fmaf(a0.z, we, acc[2]);  acc[3]  = fmaf(a0.w, we, acc[3]);
        acc[4]  = fmaf(a1.x, we, acc[4]);  acc[5]  = fmaf(a1.y, we, acc[5]);
        acc[6]  = fmaf(a1.z, we, acc[6]);  acc[7]  = fmaf(a1.w, we, acc[7]);
        acc[8]  = fmaf(a2.x, we, acc[8]);  acc[9]  = fmaf(a2.y, we, acc[9]);
        acc[10] = fmaf(a2.z, we, acc[10]); acc[11] = fmaf(a2.w, we, acc[11]);
        acc[12] = fmaf(a3.x, we, acc[12]); acc[13] = fmaf(a3.y, we, acc[13]);
        acc[14] = fmaf(a3.z, we, acc[14]); acc[15] = fmaf(a3.w, we, acc[15]);
    }
    float del[K];
    #pragma unroll
    for (int k = 0; k < K; ++k) del[k] = acc[k];

    #pragma unroll
    for (int k = 0; k < K; ++k) h[k] = adst_c - asv[k] + del[k];
    Hw[0] = make_float4(h[0], h[1], h[2], h[3]);
    Hw[1] = make_float4(h[4], h[5], h[6], h[7]);
    Hw[2] = make_float4(h[8], h[9], h[10], h[11]);
    Hw[3] = make_float4(h[12], h[13], h[14], h[15]);

    __syncthreads();
    {
        const float4* s = (const float4*)a1w;
        float4* d = (float4*)wbuf;
        d[tid] = s[tid];
        d[tid + 512] = s[tid + 512];
    }
    __syncthreads();

    #pragma unroll
    for (int k = 0; k < K; ++k) acc[k] = a1b_c;
    #pragma unroll 4
    for (int e = 0; e < C; ++e) {
        const float we = wbuf[e*C + c];
        const float4* A = (const float4*)(Hl + e*K);
        const float4 a0 = A[0], a1 = A[1], a2 = A[2], a3 = A[3];
        acc[0]  = fmaf(a0.x, we, acc[0]);  acc[1]  = fmaf(a0.y, we, acc[1]);
        acc[2]  = fmaf(a0.z, we, acc[2]);  acc[3]  = fmaf(a0.w, we, acc[3]);
        acc[4]  = fmaf(a1.x, we, acc[4]);  acc[5]  = fmaf(a1.y, we, acc[5]);
        acc[6]  = fmaf(a1.z, we, acc[6]);  acc[7]  = fmaf(a1.w, we, acc[7]);
        acc[8]  = fmaf(a2.x, we, acc[8]);  acc[9]  = fmaf(a2.y, we, acc[9]);
        acc[10] = fmaf(a2.z, we, acc[10]); acc[11] = fmaf(a2.w, we, acc[11]);
        acc[12] = fmaf(a3.x, we, acc[12]); acc[13] = fmaf(a3.y, we, acc[13]);
        acc[14] = fmaf(a3.z, we, acc[14]); acc[15] = fmaf(a3.w, we, acc[15]);
    }
    #pragma unroll
    for (int k = 0; k < K; ++k) h[k] = fmaxf(fmaf(a1g_c, acc[k], a1bt_c), 0.0f);
    Hw[0] = make_float4(h[0], h[1], h[2], h[3]);
    Hw[1] = make_float4(h[4], h[5], h[6], h[7]);
    Hw[2] = make_float4(h[8], h[9], h[10], h[11]);
    Hw[3] = make_float4(h[12], h[13], h[14], h[15]);

    __syncthreads();
    {
        const float4* s = (const float4*)a2w;
        float4* d = (float4*)wbuf;
        d[tid] = s[tid];
        d[tid + 512] = s[tid + 512];
    }
    __syncthreads();

    float vg[K];
    #pragma unroll
    for (int k = 0; k < K; ++k) vg[k] = v[Il[k]*C + c];

    #pragma unroll
    for (int k = 0; k < K; ++k) acc[k] = a2b_c;
    #pragma unroll 4
    for (int e = 0; e < C; ++e) {
        const float we = wbuf[e*C + c];
        const float4* A = (const float4*)(Hl + e*K);
        const float4 a0 = A[0], a1 = A[1], a2 = A[2], a3 = A[3];
        acc[0]  = fmaf(a0.x, we, acc[0]);  acc[1]  = fmaf(a0.y, we, acc[1]);
        acc[2]  = fmaf(a0.z, we, acc[2]);  acc[3]  = fmaf(a0.w, we, acc[3]);
        acc[4]  = fmaf(a1.x, we, acc[4]);  acc[5]  = fmaf(a1.y, we, acc[5]);
        acc[6]  = fmaf(a1.z, we, acc[6]);  acc[7]  = fmaf(a1.w, we, acc[7]);
        acc[8]  = fmaf(a2.x, we, acc[8]);  acc[9]  = fmaf(a2.y, we, acc[9]);
        acc[10] = fmaf(a2.z, we, acc[10]); acc[11] = fmaf(a2.w, we, acc[11]);
        acc[12] = fmaf(a3.x, we, acc[12]); acc[13] = fmaf(a3.y, we, acc[13]);
        acc[14] = fmaf(a3.z, we, acc[14]); acc[15] = fmaf(a3.w, we, acc[15]);
    }

    float m = acc[0];
    #pragma unroll
    for (int k = 1; k < K; ++k) m = fmaxf(m, acc[k]);
    float s = 0.0f, ag = 0.0f;
    #pragma unroll
    for (int k = 0; k < K; ++k) {
        float e_ = __expf(acc[k] - m);
        s += e_;
        ag = fmaf(e_, vg[k] + del[k], ag);
    }
    Mlf[c] = ag / s;

    __syncthreads();
    {
        const float4* s4 = (const float4*)uw;
        float4* d = (float4*)wbuf;
        d[tid] = s4[tid];
        d[tid + 512] = s4[tid + 512];
    }
    __syncthreads();

    float facc = ub_c + x_nc;
    #pragma unroll 4
    for (int e4 = 0; e4 < 16; ++e4) {
        const float4 g4 = Ml4[e4];
        facc = fmaf(g4.x, wbuf[(e4*4+0)*C + c], facc);
        facc = fmaf(g4.y, wbuf[(e4*4+1)*C + c], facc);
        facc = fmaf(g4.z, wbuf[(e4*4+2)*C + c], facc);
        facc = fmaf(g4.w, wbuf[(e4*4+3)*C + c], facc);
    }
    out[n*C + c] = facc;
}

extern "C" void kernel_launch(void* const* d_in, const int* in_sizes, int n_in,
                              void* d_out, int out_size, void* d_ws, size_t ws_size,
                              hipStream_t stream) {
    const float* x     = (const float*)d_in[0];
    const float* pos   = (const float*)d_in[1];
    const float* w_src = (const float*)d_in[2];
    const float* w_dst = (const float*)d_in[3];
    const float* w_lin = (const float*)d_in[4];
    const float* b_lin = (const float*)d_in[5];
    const float* p1w   = (const float*)d_in[6];
    const float* p1b   = (const float*)d_in[7];
    const float* p1g   = (const float*)d_in[8];
    const float* p1bt  = (const float*)d_in[9];
    const float* p2w   = (const float*)d_in[10];
    const float* p2b   = (const float*)d_in[11];
    const float* a1w   = (const float*)d_in[12];
    const float* a1b   = (const float*)d_in[13];
    const float* a1g   = (const float*)d_in[14];
    const float* a1bt  = (const float*)d_in[15];
    const float* a2w   = (const float*)d_in[16];
    const float* a2b   = (const float*)d_in[17];
    const float* uw    = (const float*)d_in[18];
    const float* ub    = (const float*)d_in[19];
    float* out = (float*)d_out;

    char* ws    = (char*)d_ws;
    int*    idx  = (int*)ws;                                    // N*K ints
    float*  adst = (float*)(ws + (size_t)N*K*sizeof(int));
    float*  asrc = adst + (size_t)N*C;
    float*  vv   = asrc + (size_t)N*C;
    float4* pos4 = (float4*)(vv + (size_t)N*C);                 // N float4

    prep_pos4 <<<(N + 255)/256, 256, 0, stream>>>(pos, pos4);
    knn_kernel<<<N/4, 256, 0, stream>>>(pos4, idx);
    lin3_kernel<<<N, 192, 0, stream>>>(x, w_src, w_dst, w_lin, b_lin, adst, asrc, vv);
    edge_kernel<<<N/NB, 512, 0, stream>>>(x, pos, idx, adst, asrc, vv,
        p1w, p1b, p1g, p1bt, p2w, p2b, a1w, a1b, a1g, a1bt, a2w, a2b, uw, ub, out);
}

// Round 6
// 121.153 us; speedup vs baseline: 4.2860x; 1.3798x over previous
//
#include <hip/hip_runtime.h>
#include <math.h>

#define N 8192
#define C 64
#define K 16
#define NB 8
#define HS 72   // bf16 row stride (elements) for LDS tiles: 144B, 16B-aligned, bank-uniform

typedef unsigned long long u64;
typedef unsigned int u32;

typedef float  f32x4v  __attribute__((ext_vector_type(4)));
typedef __bf16 bf16x8  __attribute__((ext_vector_type(8)));

__device__ __forceinline__ unsigned short bfr(float f) {   // f32 -> bf16 RTNE
    u32 u = __float_as_uint(f);
    return (unsigned short)((u + 0x7fffu + ((u >> 16) & 1u)) >> 16);
}

// ---------------- prep: pack pos into float4 ----------------
__global__ __launch_bounds__(256) void prep_pos4(const float* __restrict__ pos,
                                                 float4* __restrict__ pos4) {
    int j = blockIdx.x * 256 + threadIdx.x;
    if (j < N) pos4[j] = make_float4(pos[3*j], pos[3*j+1], pos[3*j+2], 0.0f);
}

// ---------------- Kernel 1: KNN via threshold filter (unchanged, verified) ----------------
__global__ __launch_bounds__(256) void knn_kernel(const float4* __restrict__ pos4,
                                                  int* __restrict__ idx_out) {
    __shared__ int    s_buf[4][256];
    __shared__ double s_d[4][256];
    __shared__ double s_fd[4][K];
    __shared__ int    s_fi[4][K];

    const int tid  = threadIdx.x;
    const int w    = tid >> 6;
    const int lane = tid & 63;
    const int i    = blockIdx.x * 4 + w;

    const float4 pi = pos4[i];

    float mn = INFINITY;
    #pragma unroll 4
    for (int s = 0; s < 128; ++s) {
        const int j = (s << 6) | lane;
        const float4 pj = pos4[j];
        const float dx = pi.x - pj.x, dy = pi.y - pj.y, dz = pi.z - pj.z;
        float d = fmaf(dx, dx, fmaf(dy, dy, dz * dz));
        if (j == i) d = INFINITY;
        mn = fminf(mn, d);
    }

    u64 cur = ((u64)__float_as_uint(mn) << 32) | (u32)lane;
    float T = 0.0f;
    for (int r = 0; r < K; ++r) {
        u64 m = cur;
        #pragma unroll
        for (int off = 32; off; off >>= 1) {
            const u64 o = __shfl_xor(m, off, 64);
            m = o < m ? o : m;
        }
        if (cur == m) cur = ~0ULL;
        T = __uint_as_float((u32)(m >> 32));
    }
    const float thr = T + 1e-5f * (sqrtf(T) + T + 1.0f);

    int cnt = 0;
    #pragma unroll 4
    for (int s = 0; s < 128; ++s) {
        const int j = (s << 6) | lane;
        const float4 pj = pos4[j];
        const float dx = pi.x - pj.x, dy = pi.y - pj.y, dz = pi.z - pj.z;
        const float d  = fmaf(dx, dx, fmaf(dy, dy, dz * dz));
        const bool sel = (j != i) && (d <= thr);
        const u64 mask = __ballot(sel);
        if (sel) {
            const int p = __popcll(mask & ((1ULL << lane) - 1ULL));
            const int slot = cnt + p;
            if (slot < 256) s_buf[w][slot] = j;
        }
        cnt += (int)__popcll(mask);
    }

    if (cnt <= 256) {
        const int cn = cnt;
        const double qx = (double)pi.x, qy = (double)pi.y, qz = (double)pi.z;
        for (int sl = lane; sl < cn; sl += 64) {
            const int j = s_buf[w][sl];
            const float4 pj = pos4[j];
            const double dx = qx - (double)pj.x;
            const double dy = qy - (double)pj.y;
            const double dz = qz - (double)pj.z;
            s_d[w][sl] = dx*dx + dy*dy + dz*dz;
        }
        for (int sl = lane; sl < cn; sl += 64) {
            const int    j  = s_buf[w][sl];
            const double dj = s_d[w][sl];
            int r = 0;
            for (int e = 0; e < cn; ++e) {
                const double de = s_d[w][e];
                const int    je = s_buf[w][e];
                r += (de < dj || (de == dj && je < j)) ? 1 : 0;
            }
            if (r < K) idx_out[i*K + r] = j;
        }
    } else {
        if (lane == 0) {
            for (int kk = 0; kk < K; ++kk) { s_fd[w][kk] = 1e300; s_fi[w][kk] = 0x7fffffff; }
            const double qx = (double)pi.x, qy = (double)pi.y, qz = (double)pi.z;
            for (int j = 0; j < N; ++j) {
                if (j == i) continue;
                const float4 pj = pos4[j];
                const double dx = qx - (double)pj.x;
                const double dy = qy - (double)pj.y;
                const double dz = qz - (double)pj.z;
                const double dd = dx*dx + dy*dy + dz*dz;
                if (dd < s_fd[w][K-1] || (dd == s_fd[w][K-1] && j < s_fi[w][K-1])) {
                    int p = K - 1;
                    while (p > 0 && (dd < s_fd[w][p-1] || (dd == s_fd[w][p-1] && j < s_fi[w][p-1]))) {
                        s_fd[w][p] = s_fd[w][p-1]; s_fi[w][p] = s_fi[w][p-1]; --p;
                    }
                    s_fd[w][p] = dd; s_fi[w][p] = j;
                }
            }
            for (int kk = 0; kk < K; ++kk) idx_out[i*K + kk] = s_fi[w][kk];
        }
    }
}

// ---------------- Kernel 2: a_dst/a_src/v projections (unchanged) ----------------
__global__ __launch_bounds__(192) void lin3_kernel(const float* __restrict__ x,
    const float* __restrict__ w_src, const float* __restrict__ w_dst,
    const float* __restrict__ w_lin, const float* __restrict__ b_lin,
    float* __restrict__ a_dst, float* __restrict__ a_src, float* __restrict__ v) {
    __shared__ float xr[C];
    const int i = blockIdx.x;
    const int tid = threadIdx.x;
    if (tid < C) xr[tid] = x[i*C + tid];
    __syncthreads();
    const int cc = tid & 63;
    const int m  = tid >> 6;
    const float* w = (m == 0) ? w_dst : (m == 1) ? w_src : w_lin;
    float acc = (m == 2) ? b_lin[cc] : 0.0f;
    #pragma unroll 8
    for (int k = 0; k < C; ++k) acc += xr[k] * w[k*C + cc];
    float* o = (m == 0) ? a_dst : (m == 1) ? a_src : v;
    o[i*C + cc] = acc;
}

// ---- 16x64 @ 64x64 via 8 MFMA (A: wave-private bf16 tile, B: transposed bf16 weights) ----
__device__ __forceinline__ void mm16x64(const unsigned short* Hb, const unsigned short* wT,
                                        int c0, int sg, f32x4v acc[4]) {
    const bf16x8 a0 = *reinterpret_cast<const bf16x8*>(Hb + c0*HS + sg*8);
    const bf16x8 a1 = *reinterpret_cast<const bf16x8*>(Hb + c0*HS + 32 + sg*8);
    #pragma unroll
    for (int q = 0; q < 4; ++q) {
        const unsigned short* wr = wT + (q*16 + c0)*HS + sg*8;
        const bf16x8 b0 = *reinterpret_cast<const bf16x8*>(wr);
        const bf16x8 b1 = *reinterpret_cast<const bf16x8*>(wr + 32);
        acc[q] = __builtin_amdgcn_mfma_f32_16x16x32_bf16(a0, b0, acc[q], 0, 0, 0);
        acc[q] = __builtin_amdgcn_mfma_f32_16x16x32_bf16(a1, b1, acc[q], 0, 0, 0);
    }
}

// ---------------- Kernel 3: edge pipeline, wave-per-node, MFMA matmuls ----------------
// 512 thr = 8 waves = 8 nodes. Weights staged ONCE (bf16 transposed + f32 uw); single barrier.
// Lane (c0=tid&15, sg=(tid>>4)&3) owns D rows sg*4+r (edges) x cols q*16+c0 (channels).
__global__ __launch_bounds__(512, 4) void edge_kernel(
    const float* __restrict__ x, const float* __restrict__ pos,
    const int* __restrict__ nidx,
    const float* __restrict__ a_dst, const float* __restrict__ a_src, const float* __restrict__ v,
    const float* __restrict__ p1w, const float* __restrict__ p1b,
    const float* __restrict__ p1g, const float* __restrict__ p1bt,
    const float* __restrict__ p2w, const float* __restrict__ p2b,
    const float* __restrict__ a1w, const float* __restrict__ a1b,
    const float* __restrict__ a1g, const float* __restrict__ a1bt,
    const float* __restrict__ a2w, const float* __restrict__ a2b,
    const float* __restrict__ uw, const float* __restrict__ ub,
    float* __restrict__ out) {

    __shared__ __align__(16) unsigned short sWT[3 * C * HS];  // 27,648 B: p2w,a1w,a2w as wT[c][e] bf16
    __shared__ __align__(16) float          uwf[C * C];       // 16,384 B
    __shared__ __align__(16) unsigned short sHb[NB * K * HS]; // 18,432 B: per-wave [16 edge][72] bf16
    __shared__ __align__(16) float4         sMisc4[NB * 16];  //  2,048 B: rel, then o[]
    __shared__ int                          sIdx[NB * K];     //    512 B

    const int tid  = threadIdx.x;
    const int w    = tid >> 6;
    const int lane = tid & 63;
    const int c0   = tid & 15;
    const int sg   = (tid >> 4) & 3;
    const int n    = blockIdx.x * NB + w;

    unsigned short* Hlb = sHb + w * (K * HS);
    float4*         Ml4 = sMisc4 + w * 16;
    float*          Mlf = (float*)Ml4;
    int*            Il  = sIdx + w * K;

    // ---- one-time staging: 3 bf16 transposed weight mats + f32 uw ----
    {
        const float* mats[3] = {p2w, a1w, a2w};
        #pragma unroll
        for (int m = 0; m < 3; ++m) {
            const float4* s4 = (const float4*)mats[m];
            unsigned short* dst = sWT + m * (C * HS);
            const float4 v0 = s4[tid*2], v1 = s4[tid*2 + 1];
            const int base = tid * 8;
            const int e = base >> 6, cc = base & 63;
            dst[(cc+0)*HS + e] = bfr(v0.x); dst[(cc+1)*HS + e] = bfr(v0.y);
            dst[(cc+2)*HS + e] = bfr(v0.z); dst[(cc+3)*HS + e] = bfr(v0.w);
            dst[(cc+4)*HS + e] = bfr(v1.x); dst[(cc+5)*HS + e] = bfr(v1.y);
            dst[(cc+6)*HS + e] = bfr(v1.z); dst[(cc+7)*HS + e] = bfr(v1.w);
        }
        float4* du = (float4*)uwf;
        const float4* su = (const float4*)uw;
        du[tid] = su[tid]; du[tid + 512] = su[tid + 512];
    }
    if (lane < K) {
        const int j = nidx[n*K + lane];
        Il[lane] = j;
        float4 r;
        r.x = pos[3*n]   - pos[3*j];
        r.y = pos[3*n+1] - pos[3*j+1];
        r.z = pos[3*n+2] - pos[3*j+2];
        r.w = 0.0f;
        Ml4[lane] = r;
    }
    __syncthreads();   // the ONLY block barrier

    int c4[4];
    #pragma unroll
    for (int q = 0; q < 4; ++q) c4[q] = q*16 + c0;

    // ---- phase 1: h1 = relu(g*(rel@p1w+b)+bt), written bf16 in D-layout ----
    {
        float W0[4], W1[4], W2[4], B_[4], G_[4], BT[4];
        #pragma unroll
        for (int q = 0; q < 4; ++q) {
            const int cc = c4[q];
            W0[q] = p1w[cc]; W1[q] = p1w[C + cc]; W2[q] = p1w[2*C + cc];
            B_[q] = p1b[cc]; G_[q] = p1g[cc];     BT[q] = p1bt[cc];
        }
        #pragma unroll
        for (int r = 0; r < 4; ++r) {
            const float4 rr = Ml4[sg*4 + r];
            #pragma unroll
            for (int q = 0; q < 4; ++q) {
                float t = fmaf(rr.x, W0[q], fmaf(rr.y, W1[q], fmaf(rr.z, W2[q], B_[q])));
                t = fmaxf(fmaf(G_[q], t, BT[q]), 0.0f);
                Hlb[(sg*4 + r)*HS + c4[q]] = bfr(t);
            }
        }
    }

    // ---- phase 2: delta = h1 @ p2w + p2b ----
    f32x4v acc[4], del[4];
    #pragma unroll
    for (int q = 0; q < 4; ++q) { const float b_ = p2b[c4[q]]; acc[q] = (f32x4v){b_, b_, b_, b_}; }
    mm16x64(Hlb, sWT, c0, sg, acc);
    #pragma unroll
    for (int q = 0; q < 4; ++q) del[q] = acc[q];

    int jr[4];
    #pragma unroll
    for (int r = 0; r < 4; ++r) jr[r] = Il[sg*4 + r];
    float adstv[4];
    #pragma unroll
    for (int q = 0; q < 4; ++q) adstv[q] = a_dst[n*C + c4[q]];

    // t = adst - asrc[j] + delta  -> bf16 tile
    #pragma unroll
    for (int r = 0; r < 4; ++r) {
        #pragma unroll
        for (int q = 0; q < 4; ++q) {
            const float t = adstv[q] - a_src[jr[r]*C + c4[q]] + acc[q][r];
            Hlb[(sg*4 + r)*HS + c4[q]] = bfr(t);
        }
    }

    // ---- phase 3: h2 = relu(g*(t@a1w+b)+bt) ----
    #pragma unroll
    for (int q = 0; q < 4; ++q) { const float b_ = a1b[c4[q]]; acc[q] = (f32x4v){b_, b_, b_, b_}; }
    mm16x64(Hlb, sWT + C*HS, c0, sg, acc);
    #pragma unroll
    for (int q = 0; q < 4; ++q) {
        const float g_ = a1g[c4[q]], bt_ = a1bt[c4[q]];
        #pragma unroll
        for (int r = 0; r < 4; ++r) {
            const float h2 = fmaxf(fmaf(g_, acc[q][r], bt_), 0.0f);
            Hlb[(sg*4 + r)*HS + c4[q]] = bfr(h2);
        }
    }

    // ---- phase 4: alpha = h2 @ a2w + a2b ----
    #pragma unroll
    for (int q = 0; q < 4; ++q) { const float b_ = a2b[c4[q]]; acc[q] = (f32x4v){b_, b_, b_, b_}; }
    mm16x64(Hlb, sWT + 2*C*HS, c0, sg, acc);

    // ---- softmax over 16 edges per channel (local 4 + shfl_xor 16/32) + aggregation ----
    float o_[4];
    #pragma unroll
    for (int q = 0; q < 4; ++q) {
        float vgq[4];
        #pragma unroll
        for (int r = 0; r < 4; ++r) vgq[r] = v[jr[r]*C + c4[q]];
        float lm = fmaxf(fmaxf(acc[q][0], acc[q][1]), fmaxf(acc[q][2], acc[q][3]));
        lm = fmaxf(lm, __shfl_xor(lm, 16, 64));
        lm = fmaxf(lm, __shfl_xor(lm, 32, 64));
        float ls = 0.0f, lo = 0.0f;
        #pragma unroll
        for (int r = 0; r < 4; ++r) {
            const float e_ = __expf(acc[q][r] - lm);
            ls += e_;
            lo = fmaf(e_, vgq[r] + del[q][r], lo);
        }
        ls += __shfl_xor(ls, 16, 64); ls += __shfl_xor(ls, 32, 64);
        lo += __shfl_xor(lo, 16, 64); lo += __shfl_xor(lo, 32, 64);
        o_[q] = lo / ls;
    }
    if (sg == 0) {
        #pragma unroll
        for (int q = 0; q < 4; ++q) Mlf[c4[q]] = o_[q];
    }

    // ---- epilogue (f32): out = o @ uw + ub + x ----
    float facc = ub[lane] + x[n*C + lane];
    #pragma unroll 4
    for (int e4 = 0; e4 < 16; ++e4) {
        const float4 g4 = Ml4[e4];
        facc = fmaf(g4.x, uwf[(e4*4+0)*C + lane], facc);
        facc = fmaf(g4.y, uwf[(e4*4+1)*C + lane], facc);
        facc = fmaf(g4.z, uwf[(e4*4+2)*C + lane], facc);
        facc = fmaf(g4.w, uwf[(e4*4+3)*C + lane], facc);
    }
    out[n*C + lane] = facc;
}

extern "C" void kernel_launch(void* const* d_in, const int* in_sizes, int n_in,
                              void* d_out, int out_size, void* d_ws, size_t ws_size,
                              hipStream_t stream) {
    const float* x     = (const float*)d_in[0];
    const float* pos   = (const float*)d_in[1];
    const float* w_src = (const float*)d_in[2];
    const float* w_dst = (const float*)d_in[3];
    const float* w_lin = (const float*)d_in[4];
    const float* b_lin = (const float*)d_in[5];
    const float* p1w   = (const float*)d_in[6];
    const float* p1b   = (const float*)d_in[7];
    const float* p1g   = (const float*)d_in[8];
    const float* p1bt  = (const float*)d_in[9];
    const float* p2w   = (const float*)d_in[10];
    const float* p2b   = (const float*)d_in[11];
    const float* a1w   = (const float*)d_in[12];
    const float* a1b   = (const float*)d_in[13];
    const float* a1g   = (const float*)d_in[14];
    const float* a1bt  = (const float*)d_in[15];
    const float* a2w   = (const float*)d_in[16];
    const float* a2b   = (const float*)d_in[17];
    const float* uw    = (const float*)d_in[18];
    const float* ub    = (const float*)d_in[19];
    float* out = (float*)d_out;

    char* ws    = (char*)d_ws;
    int*    idx  = (int*)ws;                                    // N*K ints
    float*  adst = (float*)(ws + (size_t)N*K*sizeof(int));
    float*  asrc = adst + (size_t)N*C;
    float*  vv   = asrc + (size_t)N*C;
    float4* pos4 = (float4*)(vv + (size_t)N*C);                 // N float4

    prep_pos4 <<<(N + 255)/256, 256, 0, stream>>>(pos, pos4);
    knn_kernel<<<N/4, 256, 0, stream>>>(pos4, idx);
    lin3_kernel<<<N, 192, 0, stream>>>(x, w_src, w_dst, w_lin, b_lin, adst, asrc, vv);
    edge_kernel<<<N/NB, 512, 0, stream>>>(x, pos, idx, adst, asrc, vv,
        p1w, p1b, p1g, p1bt, p2w, p2b, a1w, a1b, a1g, a1bt, a2w, a2b, uw, ub, out);
}